// Round 1
// baseline (2334.671 us; speedup 1.0000x reference)
//
#include <hip/hip_runtime.h>
#include <hip/hip_bf16.h>

#define S_ 64
#define B_ 64
#define E_ 512
#define H_ 512
#define V_ 32000
#define G4 2048   // 4*H
#define SB 4096   // S*B

typedef __attribute__((ext_vector_type(8))) short short8;
typedef __attribute__((ext_vector_type(4))) float f32x4;

static __device__ __forceinline__ unsigned short f2bf(float f) {
  unsigned u = __float_as_uint(f);
  u += 0x7fff + ((u >> 16) & 1);   // RNE
  return (unsigned short)(u >> 16);
}
static __device__ __forceinline__ float sigm(float x) {
  return 1.f / (1.f + expf(-x));
}

__global__ void k_f2bf(const float* __restrict__ in, unsigned short* __restrict__ out, int n) {
  int i = blockIdx.x * blockDim.x + threadIdx.x;
  int stride = gridDim.x * blockDim.x;
  for (; i < n; i += stride) out[i] = f2bf(in[i]);
}

__global__ void k_addbias(const float* __restrict__ a, const float* __restrict__ b,
                          float* __restrict__ out, int n) {
  int i = blockIdx.x * blockDim.x + threadIdx.x;
  if (i < n) out[i] = a[i] + b[i];
}

// X[t*64+b, :] = bf16(emb[idx(t,b)]);  idx = (t==0) ? Y[b,1] : Y[b,t-1]
__global__ void k_gather(const int* __restrict__ Y, const float* __restrict__ emb,
                         unsigned short* __restrict__ X) {
  int sb = blockIdx.x;
  int t = sb >> 6, b = sb & 63;
  int idx = (t == 0) ? Y[b * S_ + 1] : Y[b * S_ + t - 1];
  const float* src = emb + (size_t)idx * E_;
  unsigned short* dst = X + (size_t)sb * E_;
  for (int e = threadIdx.x; e < E_; e += blockDim.x) dst[e] = f2bf(src[e]);
}

// hidden_state/cell_state (4,64,512): slabs [l0f,l0b,l1f,l1b]
__global__ void k_init(const float* __restrict__ hid, const float* __restrict__ cell,
                       unsigned short* __restrict__ h0i, unsigned short* __restrict__ h1i,
                       float* __restrict__ c0, float* __restrict__ c1) {
  int i = blockIdx.x * blockDim.x + threadIdx.x;
  if (i >= 4 * B_ * H_) return;
  int slab = i >> 15;       // / 32768
  int rem = i & 32767;
  if (slab < 2) { h0i[slab * 32768 + rem] = f2bf(hid[i]); c0[slab * 32768 + rem] = cell[i]; }
  else          { h1i[(slab - 2) * 32768 + rem] = f2bf(hid[i]); c1[(slab - 2) * 32768 + rem] = cell[i]; }
}

// C[M,N] = A[M,K](bf16) @ B[N,K](bf16)^T + bias[N], fp32 out.
// PERMUTE: output row sb=t*64+b is written to row b*64+t (S=B=64).
#define BM 128
#define BN 128
#define BKk 32
#define LDP 40   // padded LDS row (elements)

template <bool PERMUTE>
__global__ __launch_bounds__(256) void k_gemm_nt(
    const unsigned short* __restrict__ A, const unsigned short* __restrict__ B,
    const float* __restrict__ bias, float* __restrict__ C,
    int M, int N, int K, int nTN) {
  __shared__ unsigned short Als[BM * LDP];
  __shared__ unsigned short Bls[BN * LDP];
  int tid = threadIdx.x;
  int bm = blockIdx.x / nTN, bn = blockIdx.x % nTN;
  int w = tid >> 6, l = tid & 63;
  int wr = w >> 1, wc = w & 1;
  int lr = l & 15, lk = (l >> 4) * 8;
  f32x4 acc[4][4] = {};
  for (int kk = 0; kk < K; kk += BKk) {
    __syncthreads();
#pragma unroll
    for (int i = 0; i < 2; i++) {
      int c = tid + i * 256;           // 512 16B chunks per tile
      int row = c >> 2, sub = c & 3;
      *(int4*)&Als[row * LDP + sub * 8] =
          *(const int4*)&A[(size_t)(bm * BM + row) * K + kk + sub * 8];
      *(int4*)&Bls[row * LDP + sub * 8] =
          *(const int4*)&B[(size_t)(bn * BN + row) * K + kk + sub * 8];
    }
    __syncthreads();
    short8 af[4], bfr[4];
#pragma unroll
    for (int r = 0; r < 4; r++)
      af[r] = *(const short8*)&Als[(wr * 64 + r * 16 + lr) * LDP + lk];
#pragma unroll
    for (int c4 = 0; c4 < 4; c4++)
      bfr[c4] = *(const short8*)&Bls[(wc * 64 + c4 * 16 + lr) * LDP + lk];
#pragma unroll
    for (int r = 0; r < 4; r++)
#pragma unroll
      for (int c4 = 0; c4 < 4; c4++)
        acc[r][c4] = __builtin_amdgcn_mfma_f32_16x16x32_bf16(af[r], bfr[c4], acc[r][c4], 0, 0, 0);
  }
  int rbase = bm * BM + wr * 64 + (l >> 4) * 4;
  int cbase = bn * BN + wc * 64 + lr;
#pragma unroll
  for (int r = 0; r < 4; r++) {
#pragma unroll
    for (int c4 = 0; c4 < 4; c4++) {
      int cc = cbase + c4 * 16;
      float bv = bias[cc];
#pragma unroll
      for (int j = 0; j < 4; j++) {
        int rr = rbase + r * 16 + j;
        size_t orow = PERMUTE ? (size_t)((rr & 63) * 64 + (rr >> 6)) : (size_t)rr;
        C[orow * (size_t)N + cc] = acc[r][c4][j] + bv;
      }
    }
  }
}

// One LSTM timestep, both directions of one layer.
// grid: 64 blocks (d = blk>>5, jtile = blk&31), 256 threads (wave = batch-16 tile).
// gates[b,n] = G[d, t*64+b, n] + h_prev[d,b,:] @ whh[d,n,:]
__global__ __launch_bounds__(256) void k_lstm_step(
    const unsigned short* __restrict__ hbase, int hstride, int hdoff,
    const unsigned short* __restrict__ whh,   // (2,2048,512) bf16
    const float* __restrict__ G,              // (2,4096,2048) fp32
    float* __restrict__ cbuf,                 // (2,64,512) fp32
    unsigned short* __restrict__ Hout,        // (4096,1024) bf16, col d*512+j
    int t) {
  int w = threadIdx.x >> 6, l = threadIdx.x & 63;
  int d = blockIdx.x >> 5;
  int jt = blockIdx.x & 31;
  int mt = w;
  int lr = l & 15, lk = (l >> 4) * 8;
  const unsigned short* hp = hbase + (size_t)d * hdoff;
  const unsigned short* W = whh + (size_t)d * G4 * H_;
  f32x4 acc[4] = {};
  for (int kk = 0; kk < H_; kk += 32) {
    short8 a = *(const short8*)&hp[(size_t)(mt * 16 + lr) * hstride + kk + lk];
#pragma unroll
    for (int g = 0; g < 4; g++) {
      short8 bfr = *(const short8*)&W[(size_t)(g * H_ + jt * 16 + lr) * H_ + kk + lk];
      acc[g] = __builtin_amdgcn_mfma_f32_16x16x32_bf16(a, bfr, acc[g], 0, 0, 0);
    }
  }
  const float* Gd = G + (size_t)d * SB * G4 + (size_t)t * B_ * G4;
  float* cd = cbuf + d * B_ * H_;
  int j = jt * 16 + lr;
#pragma unroll
  for (int jj = 0; jj < 4; jj++) {
    int b = mt * 16 + (l >> 4) * 4 + jj;
    float gi = acc[0][jj] + Gd[(size_t)b * G4 + j];
    float gf = acc[1][jj] + Gd[(size_t)b * G4 + 512 + j];
    float gg = acc[2][jj] + Gd[(size_t)b * G4 + 1024 + j];
    float go = acc[3][jj] + Gd[(size_t)b * G4 + 1536 + j];
    float c = sigm(gf) * cd[b * H_ + j] + sigm(gi) * tanhf(gg);
    cd[b * H_ + j] = c;
    float h = sigm(go) * tanhf(c);
    Hout[(size_t)(t * B_ + b) * 1024 + d * 512 + j] = f2bf(h);
  }
}

extern "C" void kernel_launch(void* const* d_in, const int* in_sizes, int n_in,
                              void* d_out, int out_size, void* d_ws, size_t ws_size,
                              hipStream_t stream) {
  const float* hidden = (const float*)d_in[0];
  const float* cell   = (const float*)d_in[1];
  const int*   Y      = (const int*)d_in[2];
  const float* emb    = (const float*)d_in[3];
  const float* wih0   = (const float*)d_in[4];
  const float* whh0   = (const float*)d_in[5];
  const float* bih0   = (const float*)d_in[6];
  const float* bhh0   = (const float*)d_in[7];
  const float* wih1   = (const float*)d_in[8];
  const float* whh1   = (const float*)d_in[9];
  const float* bih1   = (const float*)d_in[10];
  const float* bhh1   = (const float*)d_in[11];
  const float* fcw    = (const float*)d_in[12];
  const float* fcb    = (const float*)d_in[13];

  char* ws = (char*)d_ws;
  size_t off = 0;
  auto alloc = [&](size_t bytes) {
    void* p = ws + off;
    off += (bytes + 255) & ~(size_t)255;
    return p;
  };
  unsigned short* wih0b = (unsigned short*)alloc((size_t)2 * G4 * E_ * 2);
  unsigned short* whh0b = (unsigned short*)alloc((size_t)2 * G4 * H_ * 2);
  unsigned short* wih1b = (unsigned short*)alloc((size_t)2 * G4 * 1024 * 2);
  unsigned short* whh1b = (unsigned short*)alloc((size_t)2 * G4 * H_ * 2);
  unsigned short* fcwb  = (unsigned short*)alloc((size_t)V_ * 1024 * 2);
  unsigned short* Xb    = (unsigned short*)alloc((size_t)SB * E_ * 2);
  unsigned short* H0    = (unsigned short*)alloc((size_t)SB * 1024 * 2);
  unsigned short* O1    = (unsigned short*)alloc((size_t)SB * 1024 * 2);
  unsigned short* h0i   = (unsigned short*)alloc((size_t)2 * B_ * H_ * 2);
  unsigned short* h1i   = (unsigned short*)alloc((size_t)2 * B_ * H_ * 2);
  float* c0  = (float*)alloc((size_t)2 * B_ * H_ * 4);
  float* c1  = (float*)alloc((size_t)2 * B_ * H_ * 4);
  float* b0s = (float*)alloc((size_t)2 * G4 * 4);
  float* b1s = (float*)alloc((size_t)2 * G4 * 4);
  (void)ws_size;

  // Gate pre-activation buffers live in d_out (fully consumed before final GEMM).
  float* G0 = (float*)d_out;
  float* G1 = G0 + (size_t)2 * SB * G4;

  // --- prep ---
  k_f2bf<<<2048, 256, 0, stream>>>(wih0, wih0b, 2 * G4 * E_);
  k_f2bf<<<2048, 256, 0, stream>>>(whh0, whh0b, 2 * G4 * H_);
  k_f2bf<<<2048, 256, 0, stream>>>(wih1, wih1b, 2 * G4 * 1024);
  k_f2bf<<<2048, 256, 0, stream>>>(whh1, whh1b, 2 * G4 * H_);
  k_f2bf<<<4096, 256, 0, stream>>>(fcw, fcwb, V_ * 1024);
  k_addbias<<<16, 256, 0, stream>>>(bih0, bhh0, b0s, 2 * G4);
  k_addbias<<<16, 256, 0, stream>>>(bih1, bhh1, b1s, 2 * G4);
  k_gather<<<SB, 256, 0, stream>>>(Y, emb, Xb);
  k_init<<<512, 256, 0, stream>>>(hidden, cell, h0i, h1i, c0, c1);

  // --- layer-0 input gates: G0[d] = X @ wih0[d]^T + b0[d] ---
  for (int d = 0; d < 2; d++)
    k_gemm_nt<false><<<(SB / BM) * (G4 / BN), 256, 0, stream>>>(
        Xb, wih0b + (size_t)d * G4 * E_, b0s + d * G4, G0 + (size_t)d * SB * G4,
        SB, G4, E_, G4 / BN);

  // --- layer-0 recurrence ---
  for (int t = 0; t < S_; t++) {
    const unsigned short* hb = t ? (H0 + (size_t)(t - 1) * B_ * 1024) : h0i;
    k_lstm_step<<<64, 256, 0, stream>>>(hb, t ? 1024 : H_, t ? 512 : B_ * H_,
                                        whh0b, G0, c0, H0, t);
  }

  // --- layer-1 input gates: G1[d] = H0 @ wih1[d]^T + b1[d] ---
  for (int d = 0; d < 2; d++)
    k_gemm_nt<false><<<(SB / BM) * (G4 / BN), 256, 0, stream>>>(
        H0, wih1b + (size_t)d * G4 * 1024, b1s + d * G4, G1 + (size_t)d * SB * G4,
        SB, G4, 1024, G4 / BN);

  // --- layer-1 recurrence ---
  for (int t = 0; t < S_; t++) {
    const unsigned short* hb = t ? (O1 + (size_t)(t - 1) * B_ * 1024) : h1i;
    k_lstm_step<<<64, 256, 0, stream>>>(hb, t ? 1024 : H_, t ? 512 : B_ * H_,
                                        whh1b, G1, c1, O1, t);
  }

  // --- final projection: out[b*64+t, v] = O1[t*64+b,:] @ fcw[v,:]^T + fcb[v] ---
  k_gemm_nt<true><<<(SB / BM) * (V_ / BN), 256, 0, stream>>>(
      O1, fcwb, fcb, (float*)d_out, SB, V_, 1024, V_ / BN);
}

// Round 2
// 1885.777 us; speedup vs baseline: 1.2380x; 1.2380x over previous
//
#include <hip/hip_runtime.h>
#include <hip/hip_bf16.h>
#include <stdint.h>

#define S_ 64
#define B_ 64
#define E_ 512
#define H_ 512
#define V_ 32000
#define G4 2048   // 4*H
#define SB 4096   // S*B
#define NG 4096   // G row width: 2 dirs * 4H

typedef __attribute__((ext_vector_type(8))) short short8;
typedef __attribute__((ext_vector_type(4))) float f32x4;

static __device__ __forceinline__ unsigned short f2bf(float f) {
  unsigned u = __float_as_uint(f);
  u += 0x7fff + ((u >> 16) & 1);   // RNE
  return (unsigned short)(u >> 16);
}
static __device__ __forceinline__ float sigm(float x) {
  return 1.f / (1.f + expf(-x));
}

__device__ __forceinline__ void gload_lds16(const void* g, void* l) {
  __builtin_amdgcn_global_load_lds(
      (const __attribute__((address_space(1))) void*)g,
      (__attribute__((address_space(3))) void*)l, 16, 0, 0);
}

// device-scope barrier among `nblk` blocks sharing counter `bar`
__device__ __forceinline__ void gbar(unsigned* bar, unsigned target) {
  __syncthreads();   // drains this wave's stores (vmcnt) before fence
  if (threadIdx.x == 0) {
    __threadfence(); // release: write back L2 so other XCDs can see h
    __hip_atomic_fetch_add(bar, 1u, __ATOMIC_RELEASE, __HIP_MEMORY_SCOPE_AGENT);
    while (__hip_atomic_load(bar, __ATOMIC_ACQUIRE, __HIP_MEMORY_SCOPE_AGENT) < target) {
    }
    __threadfence(); // acquire: invalidate L1/L2 before h reads
  }
  __syncthreads();
}

__global__ void k_f2bf(const float* __restrict__ in, unsigned short* __restrict__ out, int n) {
  int i = blockIdx.x * blockDim.x + threadIdx.x;
  int stride = gridDim.x * blockDim.x;
  for (; i < n; i += stride) out[i] = f2bf(in[i]);
}

__global__ void k_addbias(const float* __restrict__ a, const float* __restrict__ b,
                          float* __restrict__ out, int n) {
  int i = blockIdx.x * blockDim.x + threadIdx.x;
  if (i < n) out[i] = a[i] + b[i];
}

// X[t*64+b, :] = bf16(emb[idx(t,b)]);  idx = (t==0) ? Y[b,1] : Y[b,t-1]
__global__ void k_gather(const int* __restrict__ Y, const float* __restrict__ emb,
                         unsigned short* __restrict__ X) {
  int sb = blockIdx.x;
  int t = sb >> 6, b = sb & 63;
  int idx = (t == 0) ? Y[b * S_ + 1] : Y[b * S_ + t - 1];
  const float* src = emb + (size_t)idx * E_;
  unsigned short* dst = X + (size_t)sb * E_;
  for (int e = threadIdx.x; e < E_; e += blockDim.x) dst[e] = f2bf(src[e]);
}

// hidden_state (4,B,H): slabs [l0f,l0b,l1f,l1b] -> bf16 h0i (layer0), h1i (layer1)
__global__ void k_init_h(const float* __restrict__ hid,
                         unsigned short* __restrict__ h0i, unsigned short* __restrict__ h1i) {
  int i = blockIdx.x * blockDim.x + threadIdx.x;
  if (i >= 4 * B_ * H_) return;
  unsigned short v = f2bf(hid[i]);
  if (i < 2 * B_ * H_) h0i[i] = v;
  else h1i[i - 2 * B_ * H_] = v;
}

// ---------------- GEMM: C[M,N] = A[M,K] @ B[N,K]^T + bias, m97-style ----------------
// global_load_lds(16B) into linear [128][32] LDS; chunk swizzle k^=(row&3) on both
// the per-lane global source and the ds_read address (involution, rule #21).
template <bool PERMUTE, bool NT>
__global__ __launch_bounds__(256) void k_gemm_nt(
    const unsigned short* __restrict__ A, const unsigned short* __restrict__ B,
    const float* __restrict__ bias, float* __restrict__ C,
    int M, int N, int K, int nTN) {
  __shared__ unsigned short Als[128 * 32];
  __shared__ unsigned short Bls[128 * 32];
  int tid = threadIdx.x;
  int bm = blockIdx.x / nTN, bn = blockIdx.x - bm * nTN;
  int w = tid >> 6, l = tid & 63;
  int wr = w >> 1, wc = w & 1;
  int lr = l & 15, hi = l >> 4;
  // staging: chunk c in [0,512); row=c>>2 (32 bf16/row), stored k-chunk=c&3,
  // source logical k-chunk = (c&3)^(row&3)
  int c0 = w * 128 + l;
  int row0 = c0 >> 2, ks0 = (((c0 & 3) ^ (row0 & 3)) * 8);
  int c1 = c0 + 64;
  int row1 = c1 >> 2, ks1 = (((c1 & 3) ^ (row1 & 3)) * 8);
  const unsigned short* Ab = A + (size_t)(bm * 128) * K;
  const unsigned short* Bb = B + (size_t)(bn * 128) * K;
  unsigned short* AlsW = &Als[w * 1024];
  unsigned short* BlsW = &Bls[w * 1024];
  int co = ((hi ^ (lr & 3)) * 8);  // read-side swizzled chunk offset (elements)
  f32x4 acc[4][4] = {};
  for (int kk = 0; kk < K; kk += 32) {
    __syncthreads();
    gload_lds16(Ab + (size_t)row0 * K + kk + ks0, AlsW);
    gload_lds16(Ab + (size_t)row1 * K + kk + ks1, AlsW + 512);
    gload_lds16(Bb + (size_t)row0 * K + kk + ks0, BlsW);
    gload_lds16(Bb + (size_t)row1 * K + kk + ks1, BlsW + 512);
    __syncthreads();  // compiler drains vmcnt(0) here
    short8 af[4], bfr[4];
#pragma unroll
    for (int r = 0; r < 4; r++)
      af[r] = *(const short8*)&Als[(wr * 64 + r * 16 + lr) * 32 + co];
#pragma unroll
    for (int c4 = 0; c4 < 4; c4++)
      bfr[c4] = *(const short8*)&Bls[(wc * 64 + c4 * 16 + lr) * 32 + co];
#pragma unroll
    for (int r = 0; r < 4; r++)
#pragma unroll
      for (int c4 = 0; c4 < 4; c4++)
        acc[r][c4] = __builtin_amdgcn_mfma_f32_16x16x32_bf16(af[r], bfr[c4], acc[r][c4], 0, 0, 0);
  }
  int rbase = bm * 128 + wr * 64 + hi * 4;
  int cbase = bn * 128 + wc * 64 + lr;
#pragma unroll
  for (int r = 0; r < 4; r++) {
#pragma unroll
    for (int c4 = 0; c4 < 4; c4++) {
      int cc = cbase + c4 * 16;
      float bv = bias[cc];
#pragma unroll
      for (int j = 0; j < 4; j++) {
        int rr = rbase + r * 16 + j;
        size_t orow = PERMUTE ? (size_t)((rr & 63) * 64 + (rr >> 6)) : (size_t)rr;
        float v = acc[r][c4][j] + bv;
        float* p = &C[orow * (size_t)N + cc];
        if (NT) __builtin_nontemporal_store(v, p);
        else *p = v;
      }
    }
  }
}

// ---------------- persistent bidirectional LSTM layer ----------------
// grid = 64 blocks: d = blk>>5 (direction), jt = blk&31 (16-col j tile).
// Weights (4 gates x 16 j x 512 K bf16 = 64KB) staged once in LDS (padded rows).
// c held in registers; h exchanged via global + per-direction device barrier.
#define LDW 520   // 512 + 8 pad elements -> 1040B row stride (16B-aligned, bank-uniform)

__global__ __launch_bounds__(256) void k_lstm_layer(
    const unsigned short* __restrict__ hinit,  // (2,B,H) bf16
    const float* __restrict__ cinit,           // (2,B,H) fp32 (layer slice of cell_state)
    const unsigned short* __restrict__ whh,    // (2,2048,512) bf16
    const float* __restrict__ G,               // (SB, NG) fp32; col = d*2048 + g*512 + j
    unsigned short* __restrict__ Hout,         // (SB, 1024) bf16; col = d*512 + j
    unsigned* __restrict__ bar) {              // bar[d], zeroed by host
  __shared__ unsigned short Wls[64 * LDW];
  int tid = threadIdx.x;
  int d = blockIdx.x >> 5, jt = blockIdx.x & 31;
  int w = tid >> 6, l = tid & 63;
  int lr = l & 15, hi = l >> 4;

  const unsigned short* Wd = whh + (size_t)d * (G4 * H_);
  for (int c = tid; c < 64 * 64; c += 256) {     // 64 rows x 64 16B-chunks
    int row = c >> 6, ck = c & 63;
    int g = row >> 4, r16 = row & 15;
    *(int4*)&Wls[row * LDW + ck * 8] =
        *(const int4*)&Wd[(size_t)(g * H_ + jt * 16 + r16) * H_ + ck * 8];
  }

  int j = jt * 16 + lr;
  int b0 = w * 16 + hi * 4;
  f32x4 creg;
  {
    const float* cd = cinit + (size_t)d * (B_ * H_);
#pragma unroll
    for (int jj = 0; jj < 4; jj++) creg[jj] = cd[(size_t)(b0 + jj) * H_ + j];
  }
  __syncthreads();

  const float* G_dj = G + d * G4;
  float gv[4][4];
  auto preloadG = [&](int t) {
#pragma unroll
    for (int jj = 0; jj < 4; jj++) {
      const float* Gb = G_dj + (size_t)(t * B_ + b0 + jj) * NG;
#pragma unroll
      for (int g = 0; g < 4; g++) gv[g][jj] = Gb[g * 512 + j];
    }
  };
  preloadG(0);
  unsigned* mybar = bar + d;

  for (int t = 0; t < S_; ++t) {
    const unsigned short* hp = (t == 0) ? hinit + (size_t)d * (B_ * H_)
                                        : Hout + (size_t)(t - 1) * B_ * 1024 + d * 512;
    size_t hstr = (t == 0) ? (size_t)H_ : 1024;
    const unsigned short* arow = hp + (size_t)(w * 16 + lr) * hstr + hi * 8;
    f32x4 acc[4] = {};
#pragma unroll
    for (int ki = 0; ki < 16; ki++) {
      short8 a = *(const short8*)&arow[ki * 32];
#pragma unroll
      for (int g = 0; g < 4; g++) {
        short8 bfr = *(const short8*)&Wls[(g * 16 + lr) * LDW + ki * 32 + hi * 8];
        acc[g] = __builtin_amdgcn_mfma_f32_16x16x32_bf16(a, bfr, acc[g], 0, 0, 0);
      }
    }
    unsigned short* Ho = Hout + (size_t)t * B_ * 1024 + d * 512;
#pragma unroll
    for (int jj = 0; jj < 4; jj++) {
      float gi = acc[0][jj] + gv[0][jj];
      float gf = acc[1][jj] + gv[1][jj];
      float gg = acc[2][jj] + gv[2][jj];
      float go = acc[3][jj] + gv[3][jj];
      float c = sigm(gf) * creg[jj] + sigm(gi) * tanhf(gg);
      creg[jj] = c;
      Ho[(size_t)(b0 + jj) * 1024 + j] = f2bf(sigm(go) * tanhf(c));
    }
    if (t + 1 < S_) {
      preloadG(t + 1);                       // issue next G loads before the spin
      gbar(mybar, (unsigned)(t + 1) * 32u);  // 32 blocks per direction
    }
  }
}

extern "C" void kernel_launch(void* const* d_in, const int* in_sizes, int n_in,
                              void* d_out, int out_size, void* d_ws, size_t ws_size,
                              hipStream_t stream) {
  const float* hidden = (const float*)d_in[0];
  const float* cell   = (const float*)d_in[1];
  const int*   Y      = (const int*)d_in[2];
  const float* emb    = (const float*)d_in[3];
  const float* wih0   = (const float*)d_in[4];
  const float* whh0   = (const float*)d_in[5];
  const float* bih0   = (const float*)d_in[6];
  const float* bhh0   = (const float*)d_in[7];
  const float* wih1   = (const float*)d_in[8];
  const float* whh1   = (const float*)d_in[9];
  const float* bih1   = (const float*)d_in[10];
  const float* bhh1   = (const float*)d_in[11];
  const float* fcw    = (const float*)d_in[12];
  const float* fcb    = (const float*)d_in[13];

  char* ws = (char*)d_ws;
  size_t off = 0;
  auto alloc = [&](size_t bytes) {
    void* p = ws + off;
    off += (bytes + 255) & ~(size_t)255;
    return p;
  };
  unsigned short* wih0b = (unsigned short*)alloc((size_t)2 * G4 * E_ * 2);
  unsigned short* whh0b = (unsigned short*)alloc((size_t)2 * G4 * H_ * 2);
  unsigned short* wih1b = (unsigned short*)alloc((size_t)2 * G4 * 1024 * 2);
  unsigned short* whh1b = (unsigned short*)alloc((size_t)2 * G4 * H_ * 2);
  unsigned short* fcwb  = (unsigned short*)alloc((size_t)V_ * 1024 * 2);
  unsigned short* Xb    = (unsigned short*)alloc((size_t)SB * E_ * 2);
  unsigned short* H0    = (unsigned short*)alloc((size_t)SB * 1024 * 2);
  unsigned short* O1    = (unsigned short*)alloc((size_t)SB * 1024 * 2);
  unsigned short* h0i   = (unsigned short*)alloc((size_t)2 * B_ * H_ * 2);
  unsigned short* h1i   = (unsigned short*)alloc((size_t)2 * B_ * H_ * 2);
  float* b0s = (float*)alloc((size_t)2 * G4 * 4);
  float* b1s = (float*)alloc((size_t)2 * G4 * 4);
  unsigned* bars = (unsigned*)alloc(256);   // bar0[2], bar1[2]
  (void)ws_size;

  // Gate pre-activation buffers live in d_out (consumed before final GEMM).
  float* G0 = (float*)d_out;                 // (SB, NG)
  float* G1 = G0 + (size_t)SB * NG;

  // --- prep ---
  k_f2bf<<<2048, 256, 0, stream>>>(wih0, wih0b, 2 * G4 * E_);
  k_f2bf<<<2048, 256, 0, stream>>>(whh0, whh0b, 2 * G4 * H_);
  k_f2bf<<<2048, 256, 0, stream>>>(wih1, wih1b, 2 * G4 * 1024);
  k_f2bf<<<2048, 256, 0, stream>>>(whh1, whh1b, 2 * G4 * H_);
  k_f2bf<<<4096, 256, 0, stream>>>(fcw, fcwb, V_ * 1024);
  k_addbias<<<16, 256, 0, stream>>>(bih0, bhh0, b0s, 2 * G4);
  k_addbias<<<16, 256, 0, stream>>>(bih1, bhh1, b1s, 2 * G4);
  k_gather<<<SB, 256, 0, stream>>>(Y, emb, Xb);
  k_init_h<<<512, 256, 0, stream>>>(hidden, h0i, h1i);
  hipMemsetAsync(bars, 0, 16, stream);

  // --- layer-0 input gates: G0 = X @ [wih0 both dirs]^T + b0 ---
  k_gemm_nt<false, false><<<(SB / 128) * (NG / 128), 256, 0, stream>>>(
      Xb, wih0b, b0s, G0, SB, NG, E_, NG / 128);

  // --- layer-0 recurrence (persistent) ---
  k_lstm_layer<<<64, 256, 0, stream>>>(h0i, cell, whh0b, G0, H0, bars);

  // --- layer-1 input gates: G1 = H0 @ [wih1 both dirs]^T + b1 ---
  k_gemm_nt<false, false><<<(SB / 128) * (NG / 128), 256, 0, stream>>>(
      H0, wih1b, b1s, G1, SB, NG, 1024, NG / 128);

  // --- layer-1 recurrence (persistent) ---
  k_lstm_layer<<<64, 256, 0, stream>>>(h1i, cell + 2 * B_ * H_, whh1b, G1, O1, bars + 2);

  // --- final projection: out[b*64+t, v] = O1[t*64+b,:] @ fcw[v,:]^T + fcb[v] ---
  k_gemm_nt<true, true><<<(SB / 128) * (V_ / 128), 256, 0, stream>>>(
      O1, fcwb, fcb, (float*)d_out, SB, V_, 1024, V_ / 128);
}

// Round 3
// 1750.663 us; speedup vs baseline: 1.3336x; 1.0772x over previous
//
#include <hip/hip_runtime.h>
#include <hip/hip_bf16.h>
#include <stdint.h>

#define S_ 64
#define B_ 64
#define E_ 512
#define H_ 512
#define V_ 32000
#define G4 2048   // 4*H
#define SB 4096   // S*B
#define NG 4096   // G0 row width: 2 dirs * 4H

typedef __attribute__((ext_vector_type(8))) short short8;
typedef __attribute__((ext_vector_type(4))) float f32x4;

static __device__ __forceinline__ unsigned short f2bf(float f) {
  unsigned u = __float_as_uint(f);
  u += 0x7fff + ((u >> 16) & 1);   // RNE
  return (unsigned short)(u >> 16);
}
static __device__ __forceinline__ float sigm(float x) {
  return 1.f / (1.f + expf(-x));
}

__device__ __forceinline__ void gload_lds16(const void* g, void* l) {
  __builtin_amdgcn_global_load_lds(
      (const __attribute__((address_space(1))) void*)g,
      (__attribute__((address_space(3))) void*)l, 16, 0, 0);
}

// device barrier: one wbl2 (release) + one inv (acquire) per call; RELAXED spin.
__device__ __forceinline__ void dbar(unsigned* bar, unsigned target) {
  __syncthreads();  // all waves drain vmcnt before s_barrier (compiler-enforced)
  if (threadIdx.x == 0) {
    __builtin_amdgcn_fence(__ATOMIC_RELEASE, "agent");   // waitcnt + wbl2
    __hip_atomic_fetch_add(bar, 1u, __ATOMIC_RELAXED, __HIP_MEMORY_SCOPE_AGENT);
    while (__hip_atomic_load(bar, __ATOMIC_RELAXED, __HIP_MEMORY_SCOPE_AGENT) < target)
      __builtin_amdgcn_s_sleep(2);
    __builtin_amdgcn_fence(__ATOMIC_ACQUIRE, "agent");   // inv
  }
  __syncthreads();
}

__global__ void k_f2bf(const float* __restrict__ in, unsigned short* __restrict__ out, int n) {
  int i = blockIdx.x * blockDim.x + threadIdx.x;
  int stride = gridDim.x * blockDim.x;
  for (; i < n; i += stride) out[i] = f2bf(in[i]);
}

__global__ void k_addbias(const float* __restrict__ a, const float* __restrict__ b,
                          float* __restrict__ out, int n) {
  int i = blockIdx.x * blockDim.x + threadIdx.x;
  if (i < n) out[i] = a[i] + b[i];
}

__global__ void k_gather(const int* __restrict__ Y, const float* __restrict__ emb,
                         unsigned short* __restrict__ X) {
  int sb = blockIdx.x;
  int t = sb >> 6, b = sb & 63;
  int idx = (t == 0) ? Y[b * S_ + 1] : Y[b * S_ + t - 1];
  const float* src = emb + (size_t)idx * E_;
  unsigned short* dst = X + (size_t)sb * E_;
  for (int e = threadIdx.x; e < E_; e += blockDim.x) dst[e] = f2bf(src[e]);
}

__global__ void k_init_h(const float* __restrict__ hid,
                         unsigned short* __restrict__ h0i, unsigned short* __restrict__ h1i) {
  int i = blockIdx.x * blockDim.x + threadIdx.x;
  if (i >= 4 * B_ * H_) return;
  unsigned short v = f2bf(hid[i]);
  if (i < 2 * B_ * H_) h0i[i] = v;
  else h1i[i - 2 * B_ * H_] = v;
}

// ---------------- GEMM: C[M,N] = A[M,K] @ B[N,K]^T + bias (m97-style) ----------------
template <bool PERMUTE, bool NT>
__global__ __launch_bounds__(256) void k_gemm_nt(
    const unsigned short* __restrict__ A, const unsigned short* __restrict__ B,
    const float* __restrict__ bias, float* __restrict__ C,
    int M, int N, int K, int nTN) {
  __shared__ unsigned short Als[128 * 32];
  __shared__ unsigned short Bls[128 * 32];
  int tid = threadIdx.x;
  int bm = blockIdx.x / nTN, bn = blockIdx.x - bm * nTN;
  int w = tid >> 6, l = tid & 63;
  int wr = w >> 1, wc = w & 1;
  int lr = l & 15, hi = l >> 4;
  int c0 = w * 128 + l;
  int row0 = c0 >> 2, ks0 = (((c0 & 3) ^ (row0 & 3)) * 8);
  int c1 = c0 + 64;
  int row1 = c1 >> 2, ks1 = (((c1 & 3) ^ (row1 & 3)) * 8);
  const unsigned short* Ab = A + (size_t)(bm * 128) * K;
  const unsigned short* Bb = B + (size_t)(bn * 128) * K;
  unsigned short* AlsW = &Als[w * 1024];
  unsigned short* BlsW = &Bls[w * 1024];
  int co = ((hi ^ (lr & 3)) * 8);
  f32x4 acc[4][4] = {};
  for (int kk = 0; kk < K; kk += 32) {
    __syncthreads();
    gload_lds16(Ab + (size_t)row0 * K + kk + ks0, AlsW);
    gload_lds16(Ab + (size_t)row1 * K + kk + ks1, AlsW + 512);
    gload_lds16(Bb + (size_t)row0 * K + kk + ks0, BlsW);
    gload_lds16(Bb + (size_t)row1 * K + kk + ks1, BlsW + 512);
    __syncthreads();
    short8 af[4], bfr[4];
#pragma unroll
    for (int r = 0; r < 4; r++)
      af[r] = *(const short8*)&Als[(wr * 64 + r * 16 + lr) * 32 + co];
#pragma unroll
    for (int c4 = 0; c4 < 4; c4++)
      bfr[c4] = *(const short8*)&Bls[(wc * 64 + c4 * 16 + lr) * 32 + co];
#pragma unroll
    for (int r = 0; r < 4; r++)
#pragma unroll
      for (int c4 = 0; c4 < 4; c4++)
        acc[r][c4] = __builtin_amdgcn_mfma_f32_16x16x32_bf16(af[r], bfr[c4], acc[r][c4], 0, 0, 0);
  }
  int rbase = bm * 128 + wr * 64 + hi * 4;
  int cbase = bn * 128 + wc * 64 + lr;
#pragma unroll
  for (int r = 0; r < 4; r++) {
#pragma unroll
    for (int c4 = 0; c4 < 4; c4++) {
      int cc = cbase + c4 * 16;
      float bv = bias[cc];
#pragma unroll
      for (int j = 0; j < 4; j++) {
        int rr = rbase + r * 16 + j;
        size_t orow = PERMUTE ? (size_t)((rr & 63) * 64 + (rr >> 6)) : (size_t)rr;
        float v = acc[r][c4][j] + bv;
        float* p = &C[orow * (size_t)N + cc];
        if (NT) __builtin_nontemporal_store(v, p);
        else *p = v;
      }
    }
  }
}

// ---------------- fused persistent 2-layer bidirectional LSTM ----------------
// 192 blocks: [0,64): layer 0 (d=blk>>5, jt16=blk&31, 16 j-cols, G0 precomputed);
// [64,192): layer 1 (idx=blk-64, d=idx>>6, jt8=idx&63, 8 j-cols, input gates
// computed on the fly from LDS-resident wih1/whh1 slices; layer-1 lags 1 step).
#define LDW0 520    // l0: 64 rows x (512+8)
#define LDW1 1544   // l1: 32 rows x (1536+8)
#define NBLK 192

__global__ __launch_bounds__(256) void k_fused_lstm(
    const unsigned short* __restrict__ h0i,   // (2,B,H) bf16
    const unsigned short* __restrict__ h1i,   // (2,B,H) bf16
    const float* __restrict__ cell,           // (4,B,H) fp32 [l0f,l0b,l1f,l1b]
    const unsigned short* __restrict__ whh0,  // (2,2048,512) bf16
    const unsigned short* __restrict__ wih1,  // (2,2048,1024) bf16
    const unsigned short* __restrict__ whh1,  // (2,2048,512) bf16
    const float* __restrict__ b1s,            // (2,2048) fp32
    const float* __restrict__ G0,             // (SB,NG) fp32
    unsigned short* __restrict__ H0,          // (SB,1024) bf16  layer-0 output
    unsigned short* __restrict__ O1,          // (SB,1024) bf16  layer-1 output
    unsigned* __restrict__ bar) {
  __shared__ unsigned short SM[32 * LDW1];    // 98,816 B (l0 uses 66,560 of it)
  int tid = threadIdx.x;
  int w = tid >> 6, l = tid & 63;
  int lr = l & 15, hi = l >> 4;

  if (blockIdx.x < 64) {
    // ================= LAYER 0 =================
    int d = blockIdx.x >> 5, jt = blockIdx.x & 31;
    const unsigned short* Wd = whh0 + (size_t)d * (G4 * H_);
    for (int c = tid; c < 64 * 64; c += 256) {
      int row = c >> 6, ck = c & 63;
      int g = row >> 4, r16 = row & 15;
      *(int4*)&SM[row * LDW0 + ck * 8] =
          *(const int4*)&Wd[(size_t)(g * H_ + jt * 16 + r16) * H_ + ck * 8];
    }
    int j = jt * 16 + lr;
    int b0 = w * 16 + hi * 4;
    f32x4 creg;
    {
      const float* cd = cell + (size_t)d * (B_ * H_);
#pragma unroll
      for (int jj = 0; jj < 4; jj++) creg[jj] = cd[(size_t)(b0 + jj) * H_ + j];
    }
    __syncthreads();
    const float* G_dj = G0 + d * G4;
    float gv[4][4];
    auto preloadG = [&](int t) {
#pragma unroll
      for (int jj = 0; jj < 4; jj++) {
        const float* Gb = G_dj + (size_t)(t * B_ + b0 + jj) * NG;
#pragma unroll
        for (int g = 0; g < 4; g++) gv[g][jj] = Gb[g * 512 + j];
      }
    };
    preloadG(0);
    for (int t = 0; t < S_; ++t) {
      const unsigned short* hp = (t == 0) ? h0i + (size_t)d * (B_ * H_)
                                          : H0 + (size_t)(t - 1) * B_ * 1024 + d * 512;
      size_t hstr = (t == 0) ? (size_t)H_ : 1024;
      const unsigned short* arow = hp + (size_t)(w * 16 + lr) * hstr + hi * 8;
      f32x4 acc[4] = {};
#pragma unroll
      for (int ki = 0; ki < 16; ki++) {
        short8 a = *(const short8*)&arow[ki * 32];
#pragma unroll
        for (int g = 0; g < 4; g++) {
          short8 bfr = *(const short8*)&SM[(g * 16 + lr) * LDW0 + ki * 32 + hi * 8];
          acc[g] = __builtin_amdgcn_mfma_f32_16x16x32_bf16(a, bfr, acc[g], 0, 0, 0);
        }
      }
      unsigned short* Ho = H0 + (size_t)t * B_ * 1024 + d * 512;
#pragma unroll
      for (int jj = 0; jj < 4; jj++) {
        float gi = acc[0][jj] + gv[0][jj];
        float gf = acc[1][jj] + gv[1][jj];
        float gg = acc[2][jj] + gv[2][jj];
        float go = acc[3][jj] + gv[3][jj];
        float c = sigm(gf) * creg[jj] + sigm(gi) * tanhf(gg);
        creg[jj] = c;
        Ho[(size_t)(b0 + jj) * 1024 + j] = f2bf(sigm(go) * tanhf(c));
      }
      if (t + 1 < S_) preloadG(t + 1);
      dbar(bar, (unsigned)(t + 1) * NBLK);
    }
  } else {
    // ================= LAYER 1 =================
    int idx = blockIdx.x - 64;
    int d = idx >> 6, jt8 = idx & 63;
    int j0 = jt8 * 8;
    // stage packed weight slice: 32 rows (g*8+jc) x [wih K=1024 | whh K=512]
    {
      const unsigned short* Wih = wih1 + (size_t)d * (G4 * 1024);
      const unsigned short* Whh = whh1 + (size_t)d * (G4 * H_);
      for (int c = tid; c < 32 * 192; c += 256) {
        int r = c / 192, ck = c - r * 192;
        int g = r >> 3, jc = r & 7;
        const unsigned short* src =
            (ck < 128) ? Wih + (size_t)(g * H_ + j0 + jc) * 1024 + ck * 8
                       : Whh + (size_t)(g * H_ + j0 + jc) * H_ + (ck - 128) * 8;
        *(int4*)&SM[r * LDW1 + ck * 8] = *(const int4*)src;
      }
    }
    int j = j0 + (lr & 7);
    const float* b1d = b1s + d * G4;
    float bi_ = b1d[j], bf_ = b1d[512 + j], bg_ = b1d[1024 + j], bo_ = b1d[1536 + j];
    int b0 = w * 16 + hi * 4;
    f32x4 creg = {};
    if (lr < 8) {
      const float* cd = cell + (size_t)(2 + d) * (B_ * H_);
#pragma unroll
      for (int jj = 0; jj < 4; jj++) creg[jj] = cd[(size_t)(b0 + jj) * H_ + j];
    }
    __syncthreads();
    for (int k = 0; k <= S_; ++k) {
      if (k >= 1) {
        int t = k - 1;
        const unsigned short* x1row = H0 + ((size_t)t * B_ + w * 16 + lr) * 1024 + hi * 8;
        const unsigned short* hprev = (t == 0)
            ? h1i + (size_t)d * (B_ * H_) + (size_t)(w * 16 + lr) * H_ + hi * 8
            : O1 + ((size_t)(t - 1) * B_ + w * 16 + lr) * 1024 + d * 512 + hi * 8;
        f32x4 acc0 = {}, acc1 = {};
#pragma unroll 8
        for (int ki = 0; ki < 32; ki++) {
          short8 a = *(const short8*)&x1row[ki * 32];
          short8 bA = *(const short8*)&SM[(size_t)lr * LDW1 + ki * 32 + hi * 8];
          short8 bB = *(const short8*)&SM[(size_t)(16 + lr) * LDW1 + ki * 32 + hi * 8];
          acc0 = __builtin_amdgcn_mfma_f32_16x16x32_bf16(a, bA, acc0, 0, 0, 0);
          acc1 = __builtin_amdgcn_mfma_f32_16x16x32_bf16(a, bB, acc1, 0, 0, 0);
        }
#pragma unroll 8
        for (int ki = 0; ki < 16; ki++) {
          short8 a = *(const short8*)&hprev[ki * 32];
          short8 bA = *(const short8*)&SM[(size_t)lr * LDW1 + 1024 + ki * 32 + hi * 8];
          short8 bB = *(const short8*)&SM[(size_t)(16 + lr) * LDW1 + 1024 + ki * 32 + hi * 8];
          acc0 = __builtin_amdgcn_mfma_f32_16x16x32_bf16(a, bA, acc0, 0, 0, 0);
          acc1 = __builtin_amdgcn_mfma_f32_16x16x32_bf16(a, bB, acc1, 0, 0, 0);
        }
        // lane lr<8 holds gates i (acc0) and g (acc1); partner lr+8 holds f and o.
        float pf[4], po[4];
#pragma unroll
        for (int jj = 0; jj < 4; jj++) {
          pf[jj] = __shfl_xor(acc0[jj], 8);
          po[jj] = __shfl_xor(acc1[jj], 8);
        }
        if (lr < 8) {
          unsigned short* Oo = O1 + (size_t)t * B_ * 1024 + d * 512;
#pragma unroll
          for (int jj = 0; jj < 4; jj++) {
            float gi = acc0[jj] + bi_;
            float gf = pf[jj] + bf_;
            float gg = acc1[jj] + bg_;
            float go = po[jj] + bo_;
            float c = sigm(gf) * creg[jj] + sigm(gi) * tanhf(gg);
            creg[jj] = c;
            Oo[(size_t)(b0 + jj) * 1024 + j] = f2bf(sigm(go) * tanhf(c));
          }
        }
      }
      if (k < S_) dbar(bar, (unsigned)(k + 1) * NBLK);
    }
  }
}

extern "C" void kernel_launch(void* const* d_in, const int* in_sizes, int n_in,
                              void* d_out, int out_size, void* d_ws, size_t ws_size,
                              hipStream_t stream) {
  const float* hidden = (const float*)d_in[0];
  const float* cell   = (const float*)d_in[1];
  const int*   Y      = (const int*)d_in[2];
  const float* emb    = (const float*)d_in[3];
  const float* wih0   = (const float*)d_in[4];
  const float* whh0   = (const float*)d_in[5];
  const float* bih0   = (const float*)d_in[6];
  const float* bhh0   = (const float*)d_in[7];
  const float* wih1   = (const float*)d_in[8];
  const float* whh1   = (const float*)d_in[9];
  const float* bih1   = (const float*)d_in[10];
  const float* bhh1   = (const float*)d_in[11];
  const float* fcw    = (const float*)d_in[12];
  const float* fcb    = (const float*)d_in[13];

  char* ws = (char*)d_ws;
  size_t off = 0;
  auto alloc = [&](size_t bytes) {
    void* p = ws + off;
    off += (bytes + 255) & ~(size_t)255;
    return p;
  };
  unsigned short* wih0b = (unsigned short*)alloc((size_t)2 * G4 * E_ * 2);
  unsigned short* whh0b = (unsigned short*)alloc((size_t)2 * G4 * H_ * 2);
  unsigned short* wih1b = (unsigned short*)alloc((size_t)2 * G4 * 1024 * 2);
  unsigned short* whh1b = (unsigned short*)alloc((size_t)2 * G4 * H_ * 2);
  unsigned short* fcwb  = (unsigned short*)alloc((size_t)V_ * 1024 * 2);
  unsigned short* Xb    = (unsigned short*)alloc((size_t)SB * E_ * 2);
  unsigned short* H0    = (unsigned short*)alloc((size_t)SB * 1024 * 2);
  unsigned short* O1    = (unsigned short*)alloc((size_t)SB * 1024 * 2);
  unsigned short* h0i   = (unsigned short*)alloc((size_t)2 * B_ * H_ * 2);
  unsigned short* h1i   = (unsigned short*)alloc((size_t)2 * B_ * H_ * 2);
  float* b0s = (float*)alloc((size_t)2 * G4 * 4);
  float* b1s = (float*)alloc((size_t)2 * G4 * 4);
  unsigned* bars = (unsigned*)alloc(256);
  (void)ws_size;

  // G0 lives in d_out (fully consumed before final GEMM overwrites it).
  float* G0 = (float*)d_out;   // (SB, NG) = 64 MB

  // --- prep ---
  k_f2bf<<<2048, 256, 0, stream>>>(wih0, wih0b, 2 * G4 * E_);
  k_f2bf<<<2048, 256, 0, stream>>>(whh0, whh0b, 2 * G4 * H_);
  k_f2bf<<<2048, 256, 0, stream>>>(wih1, wih1b, 2 * G4 * 1024);
  k_f2bf<<<2048, 256, 0, stream>>>(whh1, whh1b, 2 * G4 * H_);
  k_f2bf<<<4096, 256, 0, stream>>>(fcw, fcwb, V_ * 1024);
  k_addbias<<<16, 256, 0, stream>>>(bih0, bhh0, b0s, 2 * G4);
  k_addbias<<<16, 256, 0, stream>>>(bih1, bhh1, b1s, 2 * G4);
  k_gather<<<SB, 256, 0, stream>>>(Y, emb, Xb);
  k_init_h<<<512, 256, 0, stream>>>(hidden, h0i, h1i);
  hipMemsetAsync(bars, 0, 16, stream);

  // --- layer-0 input gates: G0 = X @ [wih0 both dirs]^T + b0 ---
  k_gemm_nt<false, false><<<(SB / 128) * (NG / 128), 256, 0, stream>>>(
      Xb, wih0b, b0s, G0, SB, NG, E_, NG / 128);

  // --- fused persistent recurrence (both layers, 64 barrier-steps) ---
  k_fused_lstm<<<NBLK, 256, 0, stream>>>(h0i, h1i, cell, whh0b, wih1b, whh1b,
                                         b1s, G0, H0, O1, bars);

  // --- final projection: out[b*64+t, v] = O1[t*64+b,:] @ fcw[v,:]^T + fcb[v] ---
  k_gemm_nt<true, true><<<(SB / 128) * (V_ / 128), 256, 0, stream>>>(
      O1, fcwb, fcb, (float*)d_out, SB, V_, 1024, V_ / 128);
}

// Round 4
// 1420.738 us; speedup vs baseline: 1.6433x; 1.2322x over previous
//
#include <hip/hip_runtime.h>
#include <hip/hip_bf16.h>
#include <stdint.h>

#define S_ 64
#define B_ 64
#define E_ 512
#define H_ 512
#define V_ 32000
#define G4 2048   // 4*H
#define SB 4096   // S*B
#define NG 4096   // G0 row width: 2 dirs * 4H

typedef __attribute__((ext_vector_type(8))) short short8;
typedef __attribute__((ext_vector_type(4))) float f32x4;

static __device__ __forceinline__ unsigned short f2bf(float f) {
  unsigned u = __float_as_uint(f);
  u += 0x7fff + ((u >> 16) & 1);   // RNE
  return (unsigned short)(u >> 16);
}
static __device__ __forceinline__ float sigm(float x) {
  return 1.f / (1.f + expf(-x));
}

__device__ __forceinline__ void gload_lds16(const void* g, void* l) {
  __builtin_amdgcn_global_load_lds(
      (const __attribute__((address_space(1))) void*)g,
      (__attribute__((address_space(3))) void*)l, 16, 0, 0);
}

// coherent (device-visible) 2-byte store: writes through past the XCD L2
__device__ __forceinline__ void st16_sys(unsigned short* p, unsigned short v) {
  unsigned long long a = (unsigned long long)p;
  unsigned vv = v;
  asm volatile("global_store_short %0, %1, off sc0 sc1" :: "v"(a), "v"(vv) : "memory");
}
__device__ __forceinline__ void wait_vm0() {
  asm volatile("s_waitcnt vmcnt(0)" ::: "memory");
}

// relaxed spin until *c >= tgt (agent-scope atomic load bypasses XCD L2)
__device__ __forceinline__ void spin_ge(unsigned* c, unsigned tgt) {
  while (__hip_atomic_load(c, __ATOMIC_RELAXED, __HIP_MEMORY_SCOPE_AGENT) < tgt)
    __builtin_amdgcn_s_sleep(4);
}
__device__ __forceinline__ void arrive(unsigned* c) {
  __hip_atomic_fetch_add(c, 1u, __ATOMIC_RELAXED, __HIP_MEMORY_SCOPE_AGENT);
}

// counter slot index: per (step, dir, part), 256B apart
#define CIDX(t, d, p) ((((t) * 8) + ((d) * 4) + (p)) * 64)
#define CNT_BYTES (64 * 8 * 64 * 4)

__global__ void k_f2bf(const float* __restrict__ in, unsigned short* __restrict__ out, int n) {
  int i = blockIdx.x * blockDim.x + threadIdx.x;
  int stride = gridDim.x * blockDim.x;
  for (; i < n; i += stride) out[i] = f2bf(in[i]);
}

__global__ void k_addbias(const float* __restrict__ a, const float* __restrict__ b,
                          float* __restrict__ out, int n) {
  int i = blockIdx.x * blockDim.x + threadIdx.x;
  if (i < n) out[i] = a[i] + b[i];
}

__global__ void k_gather(const int* __restrict__ Y, const float* __restrict__ emb,
                         unsigned short* __restrict__ X) {
  int sb = blockIdx.x;
  int t = sb >> 6, b = sb & 63;
  int idx = (t == 0) ? Y[b * S_ + 1] : Y[b * S_ + t - 1];
  const float* src = emb + (size_t)idx * E_;
  unsigned short* dst = X + (size_t)sb * E_;
  for (int e = threadIdx.x; e < E_; e += blockDim.x) dst[e] = f2bf(src[e]);
}

__global__ void k_init_h(const float* __restrict__ hid,
                         unsigned short* __restrict__ h0i, unsigned short* __restrict__ h1i) {
  int i = blockIdx.x * blockDim.x + threadIdx.x;
  if (i >= 4 * B_ * H_) return;
  unsigned short v = f2bf(hid[i]);
  if (i < 2 * B_ * H_) h0i[i] = v;
  else h1i[i - 2 * B_ * H_] = v;
}

// ---------------- GEMM: C[M,N] = A[M,K] @ B[N,K]^T + bias (m97-style) ----------------
template <bool PERMUTE, bool NT>
__global__ __launch_bounds__(256) void k_gemm_nt(
    const unsigned short* __restrict__ A, const unsigned short* __restrict__ B,
    const float* __restrict__ bias, float* __restrict__ C,
    int M, int N, int K, int nTN) {
  __shared__ unsigned short Als[128 * 32];
  __shared__ unsigned short Bls[128 * 32];
  int tid = threadIdx.x;
  int bm = blockIdx.x / nTN, bn = blockIdx.x - bm * nTN;
  int w = tid >> 6, l = tid & 63;
  int wr = w >> 1, wc = w & 1;
  int lr = l & 15, hi = l >> 4;
  int c0 = w * 128 + l;
  int row0 = c0 >> 2, ks0 = (((c0 & 3) ^ (row0 & 3)) * 8);
  int c1 = c0 + 64;
  int row1 = c1 >> 2, ks1 = (((c1 & 3) ^ (row1 & 3)) * 8);
  const unsigned short* Ab = A + (size_t)(bm * 128) * K;
  const unsigned short* Bb = B + (size_t)(bn * 128) * K;
  unsigned short* AlsW = &Als[w * 1024];
  unsigned short* BlsW = &Bls[w * 1024];
  int co = ((hi ^ (lr & 3)) * 8);
  f32x4 acc[4][4] = {};
  for (int kk = 0; kk < K; kk += 32) {
    __syncthreads();
    gload_lds16(Ab + (size_t)row0 * K + kk + ks0, AlsW);
    gload_lds16(Ab + (size_t)row1 * K + kk + ks1, AlsW + 512);
    gload_lds16(Bb + (size_t)row0 * K + kk + ks0, BlsW);
    gload_lds16(Bb + (size_t)row1 * K + kk + ks1, BlsW + 512);
    __syncthreads();
    short8 af[4], bfr[4];
#pragma unroll
    for (int r = 0; r < 4; r++)
      af[r] = *(const short8*)&Als[(wr * 64 + r * 16 + lr) * 32 + co];
#pragma unroll
    for (int c4 = 0; c4 < 4; c4++)
      bfr[c4] = *(const short8*)&Bls[(wc * 64 + c4 * 16 + lr) * 32 + co];
#pragma unroll
    for (int r = 0; r < 4; r++)
#pragma unroll
      for (int c4 = 0; c4 < 4; c4++)
        acc[r][c4] = __builtin_amdgcn_mfma_f32_16x16x32_bf16(af[r], bfr[c4], acc[r][c4], 0, 0, 0);
  }
  int rbase = bm * 128 + wr * 64 + hi * 4;
  int cbase = bn * 128 + wc * 64 + lr;
#pragma unroll
  for (int r = 0; r < 4; r++) {
#pragma unroll
    for (int c4 = 0; c4 < 4; c4++) {
      int cc = cbase + c4 * 16;
      float bv = bias[cc];
#pragma unroll
      for (int j = 0; j < 4; j++) {
        int rr = rbase + r * 16 + j;
        size_t orow = PERMUTE ? (size_t)((rr & 63) * 64 + (rr >> 6)) : (size_t)rr;
        float v = acc[r][c4][j] + bv;
        float* p = &C[orow * (size_t)N + cc];
        if (NT) __builtin_nontemporal_store(v, p);
        else *p = v;
      }
    }
  }
}

// ---------------- fused persistent 2-layer bidirectional LSTM (self-timed) ----------------
// 192 blocks: [0,64): layer 0 (d=blk>>5, jt=blk&31); [64,192): layer 1
// (idx=blk-64, d=idx>>6, jt8=idx&63). Producer/consumer flags, no lockstep:
//   cnt0[t][d][p] (tgt 8): H0[t] dir-d part-p published     (p = jt&3)
//   cnt1[t][d][p] (tgt 16): O1[t] dir-d part-p published    (p = jt8&3)
// h published via sc0sc1 write-through stores + vmcnt(0) + relaxed flag add;
// consumer: relaxed spin + one agent-acquire fence (buffer_inv) per step.
#define LDW0 520    // l0: 64 rows x (512+8)
#define LDW1 1544   // l1: 32 rows x (1536+8)
#define NBLK 192

__global__ __launch_bounds__(256) void k_fused_lstm(
    const unsigned short* __restrict__ h0i,   // (2,B,H) bf16
    const unsigned short* __restrict__ h1i,   // (2,B,H) bf16
    const float* __restrict__ cell,           // (4,B,H) fp32 [l0f,l0b,l1f,l1b]
    const unsigned short* __restrict__ whh0,  // (2,2048,512) bf16
    const unsigned short* __restrict__ wih1,  // (2,2048,1024) bf16
    const unsigned short* __restrict__ whh1,  // (2,2048,512) bf16
    const float* __restrict__ b1s,            // (2,2048) fp32
    const float* __restrict__ G0,             // (SB,NG) fp32
    unsigned short* __restrict__ H0,          // (SB,1024) bf16  layer-0 output
    unsigned short* __restrict__ O1,          // (SB,1024) bf16  layer-1 output
    unsigned* __restrict__ cnt0, unsigned* __restrict__ cnt1) {
  __shared__ unsigned short SM[32 * LDW1];    // 98,816 B (l0 uses 66,560 of it)
  int tid = threadIdx.x;
  int w = tid >> 6, l = tid & 63;
  int lr = l & 15, hi = l >> 4;

  if (blockIdx.x < 64) {
    // ================= LAYER 0 =================
    int d = blockIdx.x >> 5, jt = blockIdx.x & 31;
    const unsigned short* Wd = whh0 + (size_t)d * (G4 * H_);
    for (int c = tid; c < 64 * 64; c += 256) {
      int row = c >> 6, ck = c & 63;
      int g = row >> 4, r16 = row & 15;
      *(int4*)&SM[row * LDW0 + ck * 8] =
          *(const int4*)&Wd[(size_t)(g * H_ + jt * 16 + r16) * H_ + ck * 8];
    }
    int j = jt * 16 + lr;
    int b0 = w * 16 + hi * 4;
    f32x4 creg;
    {
      const float* cd = cell + (size_t)d * (B_ * H_);
#pragma unroll
      for (int jj = 0; jj < 4; jj++) creg[jj] = cd[(size_t)(b0 + jj) * H_ + j];
    }
    __syncthreads();
    const float* G_dj = G0 + d * G4;
    float gv[4][4];
    auto preloadG = [&](int t) {
#pragma unroll
      for (int jj = 0; jj < 4; jj++) {
        const float* Gb = G_dj + (size_t)(t * B_ + b0 + jj) * NG;
#pragma unroll
        for (int g = 0; g < 4; g++) gv[g][jj] = Gb[g * 512 + j];
      }
    };
    preloadG(0);
    for (int t = 0; t < S_; ++t) {
      if (t >= 1) {
        if (tid < 4) spin_ge(&cnt0[CIDX(t - 1, d, tid)], 8);
        __builtin_amdgcn_fence(__ATOMIC_ACQUIRE, "agent");
        __syncthreads();
      }
      const unsigned short* hp = (t == 0) ? h0i + (size_t)d * (B_ * H_)
                                          : H0 + (size_t)(t - 1) * B_ * 1024 + d * 512;
      size_t hstr = (t == 0) ? (size_t)H_ : 1024;
      const unsigned short* arow = hp + (size_t)(w * 16 + lr) * hstr + hi * 8;
      f32x4 acc[4] = {};
#pragma unroll
      for (int ki = 0; ki < 16; ki++) {
        short8 a = *(const short8*)&arow[ki * 32];
#pragma unroll
        for (int g = 0; g < 4; g++) {
          short8 bfr = *(const short8*)&SM[(g * 16 + lr) * LDW0 + ki * 32 + hi * 8];
          acc[g] = __builtin_amdgcn_mfma_f32_16x16x32_bf16(a, bfr, acc[g], 0, 0, 0);
        }
      }
      unsigned short* Ho = H0 + (size_t)t * B_ * 1024 + d * 512;
#pragma unroll
      for (int jj = 0; jj < 4; jj++) {
        float gi = acc[0][jj] + gv[0][jj];
        float gf = acc[1][jj] + gv[1][jj];
        float gg = acc[2][jj] + gv[2][jj];
        float go = acc[3][jj] + gv[3][jj];
        float c = sigm(gf) * creg[jj] + sigm(gi) * tanhf(gg);
        creg[jj] = c;
        st16_sys(&Ho[(size_t)(b0 + jj) * 1024 + j], f2bf(sigm(go) * tanhf(c)));
      }
      wait_vm0();
      __syncthreads();
      if (tid == 0) arrive(&cnt0[CIDX(t, d, jt & 3)]);
      if (t + 1 < S_) preloadG(t + 1);
    }
  } else {
    // ================= LAYER 1 =================
    int idx = blockIdx.x - 64;
    int d = idx >> 6, jt8 = idx & 63;
    int j0 = jt8 * 8;
    {
      const unsigned short* Wih = wih1 + (size_t)d * (G4 * 1024);
      const unsigned short* Whh = whh1 + (size_t)d * (G4 * H_);
      for (int c = tid; c < 32 * 192; c += 256) {
        int r = c / 192, ck = c - r * 192;
        int g = r >> 3, jc = r & 7;
        const unsigned short* src =
            (ck < 128) ? Wih + (size_t)(g * H_ + j0 + jc) * 1024 + ck * 8
                       : Whh + (size_t)(g * H_ + j0 + jc) * H_ + (ck - 128) * 8;
        *(int4*)&SM[r * LDW1 + ck * 8] = *(const int4*)src;
      }
    }
    int j = j0 + (lr & 7);
    const float* b1d = b1s + d * G4;
    float bi_ = b1d[j], bf_ = b1d[512 + j], bg_ = b1d[1024 + j], bo_ = b1d[1536 + j];
    int b0 = w * 16 + hi * 4;
    f32x4 creg = {};
    if (lr < 8) {
      const float* cd = cell + (size_t)(2 + d) * (B_ * H_);
#pragma unroll
      for (int jj = 0; jj < 4; jj++) creg[jj] = cd[(size_t)(b0 + jj) * H_ + j];
    }
    __syncthreads();
    for (int t = 0; t < S_; ++t) {
      // wait: H0[t] (both dirs) and O1[t-1] (own dir)
      if (tid < 8) spin_ge(&cnt0[CIDX(t, 0, 0) + tid * 64], 8);
      if (t >= 1 && tid >= 8 && tid < 12) spin_ge(&cnt1[CIDX(t - 1, d, tid - 8)], 16);
      __builtin_amdgcn_fence(__ATOMIC_ACQUIRE, "agent");
      __syncthreads();
      const unsigned short* x1row = H0 + ((size_t)t * B_ + w * 16 + lr) * 1024 + hi * 8;
      const unsigned short* hprev = (t == 0)
          ? h1i + (size_t)d * (B_ * H_) + (size_t)(w * 16 + lr) * H_ + hi * 8
          : O1 + ((size_t)(t - 1) * B_ + w * 16 + lr) * 1024 + d * 512 + hi * 8;
      f32x4 acc0 = {}, acc1 = {};
#pragma unroll 8
      for (int ki = 0; ki < 32; ki++) {
        short8 a = *(const short8*)&x1row[ki * 32];
        short8 bA = *(const short8*)&SM[(size_t)lr * LDW1 + ki * 32 + hi * 8];
        short8 bB = *(const short8*)&SM[(size_t)(16 + lr) * LDW1 + ki * 32 + hi * 8];
        acc0 = __builtin_amdgcn_mfma_f32_16x16x32_bf16(a, bA, acc0, 0, 0, 0);
        acc1 = __builtin_amdgcn_mfma_f32_16x16x32_bf16(a, bB, acc1, 0, 0, 0);
      }
#pragma unroll 8
      for (int ki = 0; ki < 16; ki++) {
        short8 a = *(const short8*)&hprev[ki * 32];
        short8 bA = *(const short8*)&SM[(size_t)lr * LDW1 + 1024 + ki * 32 + hi * 8];
        short8 bB = *(const short8*)&SM[(size_t)(16 + lr) * LDW1 + 1024 + ki * 32 + hi * 8];
        acc0 = __builtin_amdgcn_mfma_f32_16x16x32_bf16(a, bA, acc0, 0, 0, 0);
        acc1 = __builtin_amdgcn_mfma_f32_16x16x32_bf16(a, bB, acc1, 0, 0, 0);
      }
      float pf[4], po[4];
#pragma unroll
      for (int jj = 0; jj < 4; jj++) {
        pf[jj] = __shfl_xor(acc0[jj], 8);
        po[jj] = __shfl_xor(acc1[jj], 8);
      }
      if (lr < 8) {
        unsigned short* Oo = O1 + (size_t)t * B_ * 1024 + d * 512;
#pragma unroll
        for (int jj = 0; jj < 4; jj++) {
          float gi = acc0[jj] + bi_;
          float gf = pf[jj] + bf_;
          float gg = acc1[jj] + bg_;
          float go = po[jj] + bo_;
          float c = sigm(gf) * creg[jj] + sigm(gi) * tanhf(gg);
          creg[jj] = c;
          st16_sys(&Oo[(size_t)(b0 + jj) * 1024 + j], f2bf(sigm(go) * tanhf(c)));
        }
      }
      wait_vm0();
      __syncthreads();
      if (tid == 0 && t + 1 < S_) arrive(&cnt1[CIDX(t, d, jt8 & 3)]);
    }
  }
}

extern "C" void kernel_launch(void* const* d_in, const int* in_sizes, int n_in,
                              void* d_out, int out_size, void* d_ws, size_t ws_size,
                              hipStream_t stream) {
  const float* hidden = (const float*)d_in[0];
  const float* cell   = (const float*)d_in[1];
  const int*   Y      = (const int*)d_in[2];
  const float* emb    = (const float*)d_in[3];
  const float* wih0   = (const float*)d_in[4];
  const float* whh0   = (const float*)d_in[5];
  const float* bih0   = (const float*)d_in[6];
  const float* bhh0   = (const float*)d_in[7];
  const float* wih1   = (const float*)d_in[8];
  const float* whh1   = (const float*)d_in[9];
  const float* bih1   = (const float*)d_in[10];
  const float* bhh1   = (const float*)d_in[11];
  const float* fcw    = (const float*)d_in[12];
  const float* fcb    = (const float*)d_in[13];

  char* ws = (char*)d_ws;
  size_t off = 0;
  auto alloc = [&](size_t bytes) {
    void* p = ws + off;
    off += (bytes + 255) & ~(size_t)255;
    return p;
  };
  unsigned short* wih0b = (unsigned short*)alloc((size_t)2 * G4 * E_ * 2);
  unsigned short* whh0b = (unsigned short*)alloc((size_t)2 * G4 * H_ * 2);
  unsigned short* wih1b = (unsigned short*)alloc((size_t)2 * G4 * 1024 * 2);
  unsigned short* whh1b = (unsigned short*)alloc((size_t)2 * G4 * H_ * 2);
  unsigned short* fcwb  = (unsigned short*)alloc((size_t)V_ * 1024 * 2);
  unsigned short* Xb    = (unsigned short*)alloc((size_t)SB * E_ * 2);
  unsigned short* H0    = (unsigned short*)alloc((size_t)SB * 1024 * 2);
  unsigned short* O1    = (unsigned short*)alloc((size_t)SB * 1024 * 2);
  unsigned short* h0i   = (unsigned short*)alloc((size_t)2 * B_ * H_ * 2);
  unsigned short* h1i   = (unsigned short*)alloc((size_t)2 * B_ * H_ * 2);
  float* b0s = (float*)alloc((size_t)2 * G4 * 4);
  float* b1s = (float*)alloc((size_t)2 * G4 * 4);
  unsigned* cnt0 = (unsigned*)alloc(CNT_BYTES);
  unsigned* cnt1 = (unsigned*)alloc(CNT_BYTES);
  (void)ws_size;

  // G0 lives in d_out (fully consumed before final GEMM overwrites it).
  float* G0 = (float*)d_out;   // (SB, NG) = 64 MB

  // --- prep ---
  k_f2bf<<<2048, 256, 0, stream>>>(wih0, wih0b, 2 * G4 * E_);
  k_f2bf<<<2048, 256, 0, stream>>>(whh0, whh0b, 2 * G4 * H_);
  k_f2bf<<<2048, 256, 0, stream>>>(wih1, wih1b, 2 * G4 * 1024);
  k_f2bf<<<2048, 256, 0, stream>>>(whh1, whh1b, 2 * G4 * H_);
  k_f2bf<<<4096, 256, 0, stream>>>(fcw, fcwb, V_ * 1024);
  k_addbias<<<16, 256, 0, stream>>>(bih0, bhh0, b0s, 2 * G4);
  k_addbias<<<16, 256, 0, stream>>>(bih1, bhh1, b1s, 2 * G4);
  k_gather<<<SB, 256, 0, stream>>>(Y, emb, Xb);
  k_init_h<<<512, 256, 0, stream>>>(hidden, h0i, h1i);
  hipMemsetAsync(cnt0, 0, CNT_BYTES, stream);
  hipMemsetAsync(cnt1, 0, CNT_BYTES, stream);

  // --- layer-0 input gates: G0 = X @ [wih0 both dirs]^T + b0 ---
  k_gemm_nt<false, false><<<(SB / 128) * (NG / 128), 256, 0, stream>>>(
      Xb, wih0b, b0s, G0, SB, NG, E_, NG / 128);

  // --- fused persistent recurrence (self-timed chains) ---
  k_fused_lstm<<<NBLK, 256, 0, stream>>>(h0i, h1i, cell, whh0b, wih1b, whh1b,
                                         b1s, G0, H0, O1, cnt0, cnt1);

  // --- final projection: out[b*64+t, v] = O1[t*64+b,:] @ fcw[v,:]^T + fcb[v] ---
  k_gemm_nt<true, true><<<(SB / 128) * (V_ / 128), 256, 0, stream>>>(
      O1, fcwb, fcb, (float*)d_out, SB, V_, 1024, V_ / 128);
}